// Round 3
// baseline (170.005 us; speedup 1.0000x reference)
//
#include <hip/hip_runtime.h>
#include <hip/hip_bf16.h>

// Flash-attention fwd, block-causal packed docs. fp32 HBM, bf16 MFMA.
// B=1, H=8, D=128. R12:
//  - fa_fwd: BR=256, 8 waves (512 thr), 32 queries/wave as TWO l16-column
//    groups c=0,1. K/V LDS fragments read ONCE per wave, reused for both
//    columns -> LDS-read per query halved (1KB/q); tile stagings 4352->1280.
//    Grid 128 blocks = 1 block/CU, 2 waves/SIMD always co-resident from the
//    same block -> latency hiding on the critical 16-tile chain.
//  - prepack: V-transpose now via block-local LDS (coalesced fp32 loads,
//    conflict-free packed ds_write_b32 into stride-68 bf16 buffer, uint2
//    gathers, coalesced 16B output writes). Output layout identical to R11:
//    wsK  [H*S][128] bf16, 16B chunks XOR-permuted by (row&7)<<4
//    wsVT [H][S/64][128 d][64 keys] bf16, key-permuted chunks
//      (chunk j=ks*4+q: dwords = keys 32ks+4q+{0,1},{2,3},+16+{0,1},+16+{2,3}),
//      XOR-permuted by (d&7)<<4.
// Keeps: swapped-operand QK^T (lane owns one query per column group),
// P-in-registers PV, gll16 direct-to-LDS staging (linear dest + pre-swizzled
// source + swizzled read), double buffer, 1 barrier/tile, setprio on MFMA.

#define HD 128
#define BR 256
#define BC 64

typedef __attribute__((ext_vector_type(8))) short short8;
typedef __attribute__((ext_vector_type(4))) float floatx4;

__device__ inline unsigned packbf2(float lo, float hi) {
    __hip_bfloat162 h2 = __float22bfloat162_rn(make_float2(lo, hi));
    return *reinterpret_cast<unsigned*>(&h2);   // low16 = lo, high16 = hi
}
__device__ inline short bfs(float f) {
    __hip_bfloat16 b = __float2bfloat16(f);
    return *reinterpret_cast<short*>(&b);
}

__device__ inline void gll16(const void* g, void* l) {
    __builtin_amdgcn_global_load_lds(
        (const __attribute__((address_space(1))) unsigned int*)g,
        (__attribute__((address_space(3))) unsigned int*)l, 16, 0, 0);
}

// ---------------- prepack: fp32 -> bf16, swizzled ----------------
__global__ __launch_bounds__(256) void prepack(
    const float* __restrict__ K, const float* __restrict__ V,
    unsigned short* __restrict__ wsK, unsigned short* __restrict__ wsVT,
    int S)
{
    const int tid = threadIdx.x;
    const int nKblk = (8 * S) / 16;           // H*S*16 chunks / 256
    const int bid = blockIdx.x;
    if (bid < nKblk) {
        // K: one 16B output chunk (8 bf16 <- 8 fp32) per thread, coalesced.
        const int cid = bid * 256 + tid;
        const int row = cid >> 4;              // global row (h*S + r)
        const int c   = cid & 15;
        const float* src = K + (size_t)row * HD + c * 8;
        float4 f0 = *(const float4*)src;
        float4 f1 = *(const float4*)(src + 4);
        union { uint4 q; unsigned u[4]; } w;
        w.u[0] = packbf2(f0.x, f0.y); w.u[1] = packbf2(f0.z, f0.w);
        w.u[2] = packbf2(f1.x, f1.y); w.u[3] = packbf2(f1.z, f1.w);
        *(uint4*)((char*)wsK + (size_t)row * 256 + ((c * 16) ^ ((row & 7) << 4))) = w.q;
    } else {
        // V^T via LDS: block = one (h, tile).
        __shared__ __align__(8) unsigned short sV[HD * 68];  // [d][r], stride 68 bf16
        const int ntile = S >> 6;
        const int b = bid - nKblk;
        const int h = b / ntile;
        const int t = b - h * ntile;
        const float* vb = V + ((size_t)h * S + t * 64) * HD;
        // phase 1: thread = (row-pair rp, d-chunk dc): rows 2rp,2rp+1, d 16dc..+15.
        // Loads: 8-lane runs of 512B contiguous. Writes: banks (34i+rp)%32,
        // rp spans 0..31 per wave -> conflict-free ds_write_b32.
        {
            const int rp = tid >> 3;
            const int dc = tid & 7;
            const int r0 = rp * 2;
            const int d0 = dc * 16;
            const float* p0 = vb + (size_t)r0 * HD + d0;
            const float* p1 = p0 + HD;
            float4 a0 = *(const float4*)(p0 + 0),  a1 = *(const float4*)(p0 + 4);
            float4 a2 = *(const float4*)(p0 + 8),  a3 = *(const float4*)(p0 + 12);
            float4 b0 = *(const float4*)(p1 + 0),  b1 = *(const float4*)(p1 + 4);
            float4 b2 = *(const float4*)(p1 + 8),  b3 = *(const float4*)(p1 + 12);
            float av[16] = {a0.x,a0.y,a0.z,a0.w, a1.x,a1.y,a1.z,a1.w,
                            a2.x,a2.y,a2.z,a2.w, a3.x,a3.y,a3.z,a3.w};
            float bv[16] = {b0.x,b0.y,b0.z,b0.w, b1.x,b1.y,b1.z,b1.w,
                            b2.x,b2.y,b2.z,b2.w, b3.x,b3.y,b3.z,b3.w};
            #pragma unroll
            for (int i = 0; i < 16; ++i) {
                unsigned pr = packbf2(av[i], bv[i]);   // keys r0 (lo), r0+1 (hi)
                *(unsigned*)((char*)sV + ((size_t)(d0 + i) * 68 + r0) * 2) = pr;
            }
        }
        __syncthreads();
        // phase 2: thread = (d = tid>>1, jj = tid&1), 4 consecutive chunks.
        // uint2 LDS reads ~conflict-free (stride-68 rotation); output writes
        // coalesced (thread-pair covers one 128B d-row).
        const int d  = tid >> 1;
        const int jj = tid & 1;
        char* dstrow = (char*)wsVT + (((size_t)(h * ntile + t) * HD + d) * 128);
        const int dx = (d & 7) << 4;
        const unsigned short* srow = sV + (size_t)d * 68;
        #pragma unroll
        for (int u = 0; u < 4; ++u) {
            const int j  = jj * 4 + u;
            const int k0 = (j >> 2) * 32 + (j & 3) * 4;
            uint2 lo = *(const uint2*)(srow + k0);        // keys k0..k0+3
            uint2 hi = *(const uint2*)(srow + k0 + 16);   // keys k0+16..k0+19
            uint4 w = make_uint4(lo.x, lo.y, hi.x, hi.y);
            *(uint4*)(dstrow + ((j * 16) ^ dx)) = w;
        }
    }
}

// ---------------- main attention kernel ----------------
__global__ __launch_bounds__(512, 2) void fa_fwd(
    const float* __restrict__ Q,
    const unsigned short* __restrict__ wsK,
    const unsigned short* __restrict__ wsVT,
    const int* __restrict__ cu_seqlens, int n_cu,
    float* __restrict__ O,
    int S)
{
    __shared__ alignas(16) __hip_bfloat16 sK[2][BC * HD];    // 2 x 16KB
    __shared__ alignas(16) unsigned int   sVT[2][HD * 32];   // 2 x 16KB

    const int tid  = threadIdx.x;
    const int wave = tid >> 6;
    const int lane = tid & 63;
    const int quad = lane >> 4;
    const int l16  = lane & 15;
    const int kx   = (l16 & 7) << 4;        // read-side XOR (matches prepack)

    const int h = blockIdx.x & 7;           // head pinned to XCD: K/V L2 reuse
    const int g = (int)(blockIdx.x >> 3);   // 0..S/256-1
    const int q0  = g * BR;
    const int qw0 = q0 + wave * 32;         // wave's first query (column c adds c*16)

    // ---- block-uniform doc geometry ----
    int blk_ds = 0;
    for (int i = 0; i < n_cu; ++i) {
        int c = cu_seqlens[i];
        if (c <= q0) blk_ds = c;
    }
    const int k_begin = blk_ds & ~(BC - 1);
    const int ntiles  = (q0 + BR - 1 - k_begin) / BC + 1;

    // ---- staging: 4x global_load_lds dwordx4 per thread (32KB/tile/block) ----
    const char* gkb = (const char*)wsK + (size_t)h * S * 256;
    const char* gvb = (const char*)wsVT + (size_t)h * (S >> 6) * 16384;
    const int lo = wave * 1024 + lane * 16;
    auto stage = [&](int kt, int buf) {
        const char* gk = gkb + (size_t)kt * 256 + lo;
        const char* gv = gvb + (size_t)(kt >> 6) * 16384 + lo;
        char* lk = (char*)&sK[buf][0] + wave * 1024;   // wave-uniform base
        char* lv = (char*)&sVT[buf][0] + wave * 1024;
        gll16(gk, lk);            gll16(gk + 8192, lk + 8192);
        gll16(gv, lv);            gll16(gv + 8192, lv + 8192);
    };

    stage(k_begin, 0);   // issue ASAP; latency hides under prologue

    const size_t hoff = (size_t)h * S * HD;
    const float* Qh = Q + hoff;
    float*       Oh = O + hoff;

    // ---- per-lane per-column doc start ----
    int qlane[2], ds_l[2];
    #pragma unroll
    for (int c = 0; c < 2; ++c) {
        qlane[c] = qw0 + c * 16 + l16;
        int d = 0;
        for (int i = 0; i < n_cu; ++i) {
            int cc = cu_seqlens[i];
            if (cc <= qlane[c]) d = cc;
        }
        ds_l[c] = d;
    }

    // ---- Q fragments (B-operand), one per column group ----
    short8 aq[2][4];
    #pragma unroll
    for (int c = 0; c < 2; ++c) {
        const float* qp = Qh + (size_t)qlane[c] * HD + quad * 8;
        #pragma unroll
        for (int ks = 0; ks < 4; ++ks) {
            float4 a0 = *(const float4*)(qp + ks * 32);
            float4 a1 = *(const float4*)(qp + ks * 32 + 4);
            short8 a;
            a[0] = bfs(a0.x); a[1] = bfs(a0.y); a[2] = bfs(a0.z); a[3] = bfs(a0.w);
            a[4] = bfs(a1.x); a[5] = bfs(a1.y); a[6] = bfs(a1.z); a[7] = bfs(a1.w);
            aq[c][ks] = a;
        }
    }

    // oacc[c][dt][r] = O[qlane[c]][dt*16 + quad*4 + r]
    floatx4 oacc[2][8];
    #pragma unroll
    for (int c = 0; c < 2; ++c)
        #pragma unroll
        for (int dt = 0; dt < 8; ++dt) oacc[c][dt] = (floatx4){0.f, 0.f, 0.f, 0.f};
    float m_r[2] = {-1e30f, -1e30f};
    float l_r[2] = {0.f, 0.f};

    const float sl = 0.08838834764831845f * 1.4426950408889634f;

    __syncthreads();    // drains stage(k_begin) vmcnt + all waves ready

    for (int it = 0; it < ntiles; ++it) {
        const int kt  = k_begin + it * BC;
        const int buf = it & 1;

        if (it + 1 < ntiles) stage(kt + BC, buf ^ 1);

        if (kt <= qw0 + 31) {                // wave-level early-out
            const bool act0 = (kt <= qw0 + 15);
            const char* kbase = (const char*)&sK[buf][0];
            const char* vbase = (const char*)&sVT[buf][0];

            // ---- S^T = K Q^T: A-frags read once, reused for both columns ----
            floatx4 sc[2][4];
            __builtin_amdgcn_s_setprio(1);
            #pragma unroll
            for (int ct = 0; ct < 4; ++ct) {
                const int kc = kt + ct * 16;
                if (kc <= qw0 + 31) {        // wave-uniform
                    short8 a[4];
                    #pragma unroll
                    for (int ks = 0; ks < 4; ++ks)
                        a[ks] = *(const short8*)(kbase + (ct * 16 + l16) * 256
                                                 + (((ks * 4 + quad) << 4) ^ kx));
                    floatx4 c1 = (floatx4){0.f, 0.f, 0.f, 0.f};
                    #pragma unroll
                    for (int ks = 0; ks < 4; ++ks)
                        c1 = __builtin_amdgcn_mfma_f32_16x16x32_bf16(a[ks], aq[1][ks], c1, 0, 0, 0);
                    sc[1][ct] = c1;
                    if (kc <= qw0 + 15) {
                        floatx4 c0 = (floatx4){0.f, 0.f, 0.f, 0.f};
                        #pragma unroll
                        for (int ks = 0; ks < 4; ++ks)
                            c0 = __builtin_amdgcn_mfma_f32_16x16x32_bf16(a[ks], aq[0][ks], c0, 0, 0, 0);
                        sc[0][ct] = c0;
                    } else {
                        sc[0][ct] = (floatx4){-1e30f, -1e30f, -1e30f, -1e30f};
                    }
                } else {
                    sc[0][ct] = (floatx4){-1e30f, -1e30f, -1e30f, -1e30f};
                    sc[1][ct] = (floatx4){-1e30f, -1e30f, -1e30f, -1e30f};
                }
            }
            __builtin_amdgcn_s_setprio(0);

            // ---- mask + online softmax, per column (independent chains) ----
            #pragma unroll
            for (int c = 0; c < 2; ++c) {
                if (c == 0 && !act0) continue;     // wave-uniform
                #pragma unroll
                for (int ct = 0; ct < 4; ++ct) {
                    if (kt + ct * 16 <= qw0 + c * 16 + 15) {
                        #pragma unroll
                        for (int r = 0; r < 4; ++r) {
                            const int key = kt + ct * 16 + quad * 4 + r;
                            const bool valid = (key <= qlane[c]) && (key >= ds_l[c]);
                            float s = sc[c][ct][r] * sl;
                            sc[c][ct][r] = valid ? s : -1e30f;
                        }
                    }
                }
                float mx0 = fmaxf(fmaxf(sc[c][0][0], sc[c][0][1]), fmaxf(sc[c][0][2], sc[c][0][3]));
                float mx1 = fmaxf(fmaxf(sc[c][1][0], sc[c][1][1]), fmaxf(sc[c][1][2], sc[c][1][3]));
                float mx2 = fmaxf(fmaxf(sc[c][2][0], sc[c][2][1]), fmaxf(sc[c][2][2], sc[c][2][3]));
                float mx3 = fmaxf(fmaxf(sc[c][3][0], sc[c][3][1]), fmaxf(sc[c][3][2], sc[c][3][3]));
                float mx  = fmaxf(fmaxf(mx0, mx1), fmaxf(mx2, mx3));
                mx = fmaxf(mx, __shfl_xor(mx, 16, 64));
                mx = fmaxf(mx, __shfl_xor(mx, 32, 64));

                const float mnew = fmaxf(m_r[c], mx);
                const float al   = exp2f(m_r[c] - mnew);
                m_r[c] = mnew;

                float s0 = 0.f, s1 = 0.f, s2 = 0.f, s3 = 0.f;
                #pragma unroll
                for (int ct = 0; ct < 4; ++ct) {
                    float p0 = exp2f(sc[c][ct][0] - m_r[c]);
                    float p1 = exp2f(sc[c][ct][1] - m_r[c]);
                    float p2 = exp2f(sc[c][ct][2] - m_r[c]);
                    float p3 = exp2f(sc[c][ct][3] - m_r[c]);
                    sc[c][ct][0] = p0; sc[c][ct][1] = p1;
                    sc[c][ct][2] = p2; sc[c][ct][3] = p3;
                    s0 += p0; s1 += p1; s2 += p2; s3 += p3;
                }
                l_r[c] = l_r[c] * al + ((s0 + s1) + (s2 + s3));
                #pragma unroll
                for (int dt = 0; dt < 8; ++dt) {
                    #pragma unroll
                    for (int r = 0; r < 4; ++r)
                        oacc[c][dt][r] *= al;
                }
            }

            // ---- O^T += V^T P^T: V-frags read once, reused for both columns ----
            __builtin_amdgcn_s_setprio(1);
            #pragma unroll
            for (int ks = 0; ks < 2; ++ks) {
                const int kh = kt + ks * 32;
                if (kh <= qw0 + 31) {        // wave-uniform
                    union { unsigned u[4]; short8 s; } pu1, pu0;
                    pu1.u[0] = packbf2(sc[1][2*ks][0],   sc[1][2*ks][1]);
                    pu1.u[1] = packbf2(sc[1][2*ks][2],   sc[1][2*ks][3]);
                    pu1.u[2] = packbf2(sc[1][2*ks+1][0], sc[1][2*ks+1][1]);
                    pu1.u[3] = packbf2(sc[1][2*ks+1][2], sc[1][2*ks+1][3]);
                    const bool p0a = (kh <= qw0 + 15);
                    if (p0a) {
                        pu0.u[0] = packbf2(sc[0][2*ks][0],   sc[0][2*ks][1]);
                        pu0.u[1] = packbf2(sc[0][2*ks][2],   sc[0][2*ks][3]);
                        pu0.u[2] = packbf2(sc[0][2*ks+1][0], sc[0][2*ks+1][1]);
                        pu0.u[3] = packbf2(sc[0][2*ks+1][2], sc[0][2*ks+1][3]);
                    }
                    #pragma unroll
                    for (int dt = 0; dt < 8; ++dt) {
                        union { uint4 q; short8 s; } cv;
                        cv.q = *(const uint4*)(vbase + (dt * 16 + l16) * 128
                                               + (((ks * 4 + quad) << 4) ^ kx));
                        oacc[1][dt] = __builtin_amdgcn_mfma_f32_16x16x32_bf16(cv.s, pu1.s, oacc[1][dt], 0, 0, 0);
                        if (p0a)
                            oacc[0][dt] = __builtin_amdgcn_mfma_f32_16x16x32_bf16(cv.s, pu0.s, oacc[0][dt], 0, 0, 0);
                    }
                }
            }
            __builtin_amdgcn_s_setprio(0);
        }

        __syncthreads();   // drains vmcnt (next-tile stage) + readers of buf
    }

    // ---- epilogue: reduce l over quads, float4 stores, per column ----
    #pragma unroll
    for (int c = 0; c < 2; ++c) {
        float l = l_r[c];
        l += __shfl_xor(l, 16, 64);
        l += __shfl_xor(l, 32, 64);
        const float inv = 1.0f / l;
        float* op = Oh + (size_t)qlane[c] * HD + quad * 4;
        #pragma unroll
        for (int dt = 0; dt < 8; ++dt) {
            float4 st;
            st.x = oacc[c][dt][0] * inv;
            st.y = oacc[c][dt][1] * inv;
            st.z = oacc[c][dt][2] * inv;
            st.w = oacc[c][dt][3] * inv;
            *(float4*)(op + dt * 16) = st;
        }
    }
}

extern "C" void kernel_launch(void* const* d_in, const int* in_sizes, int n_in,
                              void* d_out, int out_size, void* d_ws, size_t ws_size,
                              hipStream_t stream) {
    const float* q = (const float*)d_in[0];
    const float* k = (const float*)d_in[1];
    const float* v = (const float*)d_in[2];
    const int* cu = (const int*)d_in[3];
    const int n_cu = in_sizes[3];
    const int H = 8;
    const int S = in_sizes[0] / (H * HD);   // B=1
    float* out = (float*)d_out;

    unsigned short* wsK  = (unsigned short*)d_ws;                 // 8*S*256 B
    unsigned short* wsVT = wsK + (size_t)H * S * HD;              // 8*S*256 B

    const int nKblk = (H * S) / 16;          // 2048
    const int nVblk = H * (S >> 6);          // 512
    prepack<<<dim3(nKblk + nVblk), dim3(256), 0, stream>>>(k, v, wsK, wsVT, S);

    dim3 grid(H * (S / BR));   // 128 blocks, 1 per CU
    dim3 block(512);           // 8 waves
    fa_fwd<<<grid, block, 0, stream>>>(q, wsK, wsVT, cu, n_cu, out, S);
}